// Round 8
// baseline (323.085 us; speedup 1.0000x reference)
//
#include <hip/hip_runtime.h>
#include <math.h>

typedef short bf16x8 __attribute__((ext_vector_type(8)));
typedef float f32x16 __attribute__((ext_vector_type(16)));

__device__ __forceinline__ unsigned short f2bf(float f) {
    union { float f; unsigned u; } x; x.f = f;
    unsigned r = x.u + 0x7FFFu + ((x.u >> 16) & 1u);
    return (unsigned short)(r >> 16);
}

// ---- device-scope grid barrier (sense via generation counter) ----
// cnt/gen zeroed by hipMemsetAsync before launch. Requires all blocks resident
// (cooperative launch guarantees).
__device__ __forceinline__ void grid_barrier(unsigned* cnt, unsigned* gen, unsigned nblk) {
    __syncthreads();                       // block's stores issued; vmcnt drained by barrier
    if (threadIdx.x == 0) {
        __threadfence();                   // release: flush my XCD's L2 writes
        unsigned g = __hip_atomic_load(gen, __ATOMIC_RELAXED, __HIP_MEMORY_SCOPE_AGENT);
        if (__hip_atomic_fetch_add(cnt, 1u, __ATOMIC_ACQ_REL, __HIP_MEMORY_SCOPE_AGENT) == nblk - 1u) {
            __hip_atomic_store(cnt, 0u, __ATOMIC_RELAXED, __HIP_MEMORY_SCOPE_AGENT);
            __hip_atomic_fetch_add(gen, 1u, __ATOMIC_RELEASE, __HIP_MEMORY_SCOPE_AGENT);
        } else {
            while (__hip_atomic_load(gen, __ATOMIC_ACQUIRE, __HIP_MEMORY_SCOPE_AGENT) == g)
                __builtin_amdgcn_s_sleep(2);
        }
        // acquire: invalidate stale L1/L2 lines before post-barrier reads
        (void)__hip_atomic_load(gen, __ATOMIC_ACQUIRE, __HIP_MEMORY_SCOPE_AGENT);
    }
    __syncthreads();
}

// ---- Transpose one 32-row tile of fp32 into frag-major bf16 (round-7 verified) ----
template<int NKS_T>
__device__ void transpose_tile(const float* __restrict__ W, const float* __restrict__ bias,
                               int rowbase, int rowlimit, int Kreal, int ldsrc,
                               unsigned short* __restrict__ dst, float* s, int tid)
{
    constexpr int NCHK = NKS_T / 4;
    const int r = tid >> 3, l = tid & 7;
    const int ks_l = tid >> 6, lane = tid & 63;
    const int m = lane & 31, h = lane >> 5;
    for (int kc = 0; kc < NCHK; ++kc) {
        {
            int kb = kc * 64 + l * 8;
            const bool rv = r < rowlimit;
            const float* src = W + (size_t)(rowbase + r) * ldsrc + kb;
            float v[8];
            if (rv && kb + 7 < Kreal) {
                #pragma unroll
                for (int i = 0; i < 8; ++i) v[i] = src[i];
            } else {
                #pragma unroll
                for (int i = 0; i < 8; ++i) {
                    int k = kb + i;
                    v[i] = (rv && k < Kreal) ? src[i]
                         : ((rv && k == Kreal) ? (bias ? bias[rowbase + r] : 1.0f) : 0.f);
                }
            }
            #pragma unroll
            for (int i = 0; i < 8; ++i) s[r * 66 + l * 8 + i] = v[i];
        }
        __syncthreads();
        {
            bf16x8 pk;
            #pragma unroll
            for (int j = 0; j < 8; ++j)
                pk[j] = (short)f2bf(s[m * 66 + ks_l * 16 + h * 8 + j]);
            *(bf16x8*)(dst + ((size_t)(kc * 4 + ks_l) * 64 + lane) * 8) = pk;
        }
        __syncthreads();
    }
}

// ---- Phase A body: unit u in [0,200) (round-7 verified) ----
__device__ void phaseA_unit(
    int u, int tid, float* s,
    const float* __restrict__ x,
    const float* __restrict__ W0, const float* __restrict__ W1, const float* __restrict__ W2,
    const float* __restrict__ bias0, const float* __restrict__ bias1, const float* __restrict__ bias2,
    float* __restrict__ coef, unsigned short* __restrict__ xf,
    unsigned short* __restrict__ H1f, unsigned short* __restrict__ H2f,
    unsigned short* __restrict__ Wf0, unsigned short* __restrict__ Wf1, unsigned short* __restrict__ Wf2)
{
    if (u < 32) {
        const int bt = u;
        if (tid < 32) {
            int b = bt * 32 + tid;
            float phase = x[(size_t)b * 343 + 342];
            float ps = 4.0f * phase;
            int k1 = (int)ps;
            float mu = ps - (float)k1;
            k1 &= 3;
            float mu2 = mu * mu, mu3 = mu2 * mu;
            float c0 = -0.5f * mu3 +        mu2 - 0.5f * mu;
            float c1 =  1.5f * mu3 - 2.5f * mu2 + 1.0f;
            float c2 = -1.5f * mu3 + 2.0f * mu2 + 0.5f * mu;
            float c3 =  0.5f * mu3 - 0.5f * mu2;
            float cc[4];
            cc[(k1 + 3) & 3] = c0;
            cc[k1]           = c1;
            cc[(k1 + 1) & 3] = c2;
            cc[(k1 + 2) & 3] = c3;
            *(float4*)(coef + b * 4) = make_float4(cc[0], cc[1], cc[2], cc[3]);
        }
        {
            int kk = tid >> 6, lane = tid & 63;
            size_t off = ((size_t)(bt * 36 + 32 + kk) * 64 + lane) * 8;
            bf16x8 v;
            #pragma unroll
            for (int j = 0; j < 8; ++j)
                v[j] = (short)((kk == 0 && (lane >> 5) == 0 && j == 0) ? 0x3F80 : 0);
            *(bf16x8*)(H1f + off) = v;
            *(bf16x8*)(H2f + off) = v;
        }
        transpose_tile<24>(x, nullptr, bt * 32, 32, 342, 343,
                           xf + (size_t)bt * 24 * 512, s, tid);
    } else if (u < 96) {
        int idx = u - 32, n = idx >> 4, ot = idx & 15;
        transpose_tile<24>(W0, bias0, n * 512 + ot * 32, 32, 342, 342,
                           Wf0 + (size_t)(n * 16 + ot) * 24 * 512, s, tid);
    } else if (u < 160) {
        int idx = u - 96, n = idx >> 4, ot = idx & 15;
        transpose_tile<36>(W1, bias1, n * 512 + ot * 32, 32, 512, 512,
                           Wf1 + (size_t)(n * 16 + ot) * 36 * 512, s, tid);
    } else {
        int idx = u - 160, n = idx / 10, ot = idx % 10;
        int rl = 311 - ot * 32; if (rl > 32) rl = 32;
        transpose_tile<36>(W2, bias2, n * 311 + ot * 32, rl, 512, 512,
                           Wf2 + (size_t)(n * 10 + ot) * 36 * 512, s, tid);
    }
}

// ---- Layer body (round-7 verified; grid-stride over tiles) ----
template<bool ELU, bool OUT_BF16, int KP, int OPAD>
__device__ __forceinline__ void layer_phase(
    const unsigned short* __restrict__ Wf,
    const unsigned short* __restrict__ Hf,
    const float* __restrict__ coef,
    unsigned short* __restrict__ HoutF,
    float* __restrict__ outF, int Oreal,
    float* red, int bid, int tid, int gdim)
{
    constexpr int NOT = OPAD / 32, NKS = KP / 16, KSQ = NKS / 4;
    constexpr int CH = 3, NC2 = KSQ / CH;
    const int lane = tid & 63, w = tid >> 6;
    const int m = lane & 31, h = lane >> 5;
    const size_t nstr = (size_t)NOT * NKS * 512;

    for (int t = bid; t < NOT * 32; t += gdim) {
        const int ot = t >> 5, bt = t & 31;
        const unsigned short* wbase = Wf + ((size_t)ot * NKS + w * KSQ) * 512 + (size_t)lane * 8;
        const unsigned short* bbase = Hf + ((size_t)bt * NKS + w * KSQ) * 512 + (size_t)lane * 8;

        f32x16 acc0 = {}, acc1 = {}, acc2 = {}, acc3 = {};
        bf16x8 Ab[2][CH][4], Bb[2][CH];

        #pragma unroll
        for (int sI = 0; sI < CH; ++sI) {
            Bb[0][sI] = *(const bf16x8*)(bbase + (size_t)sI * 512);
            #pragma unroll
            for (int n = 0; n < 4; ++n)
                Ab[0][sI][n] = *(const bf16x8*)(wbase + (size_t)n * nstr + (size_t)sI * 512);
        }
        #pragma unroll
        for (int c = 0; c < NC2; ++c) {
            const int cur = c & 1;
            if (c + 1 < NC2) {
                const int nxt = cur ^ 1;
                #pragma unroll
                for (int sI = 0; sI < CH; ++sI) {
                    int st = (c + 1) * CH + sI;
                    Bb[nxt][sI] = *(const bf16x8*)(bbase + (size_t)st * 512);
                    #pragma unroll
                    for (int n = 0; n < 4; ++n)
                        Ab[nxt][sI][n] = *(const bf16x8*)(wbase + (size_t)n * nstr + (size_t)st * 512);
                }
            }
            #pragma unroll
            for (int sI = 0; sI < CH; ++sI) {
                acc0 = __builtin_amdgcn_mfma_f32_32x32x16_bf16(Ab[cur][sI][0], Bb[cur][sI], acc0, 0, 0, 0);
                acc1 = __builtin_amdgcn_mfma_f32_32x32x16_bf16(Ab[cur][sI][1], Bb[cur][sI], acc1, 0, 0, 0);
                acc2 = __builtin_amdgcn_mfma_f32_32x32x16_bf16(Ab[cur][sI][2], Bb[cur][sI], acc2, 0, 0, 0);
                acc3 = __builtin_amdgcn_mfma_f32_32x32x16_bf16(Ab[cur][sI][3], Bb[cur][sI], acc3, 0, 0, 0);
            }
        }

        const int b = bt * 32 + m;
        float4 cf = *(const float4*)(coef + b * 4);
        #pragma unroll
        for (int g = 0; g < 4; ++g)
            #pragma unroll
            for (int j = 0; j < 4; ++j) {
                int rI = g * 4 + j;
                float v = cf.x * acc0[rI] + cf.y * acc1[rI] + cf.z * acc2[rI] + cf.w * acc3[rI];
                red[w * 1024 + (8 * g + 4 * h + j) * 32 + m] = v;
            }
        __syncthreads();
        {
            float vv[4];
            #pragma unroll
            for (int j = 0; j < 4; ++j) {
                int row = 8 * w + 4 * h + j;
                float v = red[row * 32 + m] + red[1024 + row * 32 + m]
                        + red[2048 + row * 32 + m] + red[3072 + row * 32 + m];
                if (ELU) v = (v > 0.f) ? v : expm1f(v);
                vv[j] = v;
            }
            if (OUT_BF16) {
                size_t off = (((size_t)bt * 36 + ot * 2 + (w >> 1)) * 64
                              + (w & 1) * 32 + m) * 8 + 4 * h;
                ushort4 pk;
                pk.x = f2bf(vv[0]); pk.y = f2bf(vv[1]); pk.z = f2bf(vv[2]); pk.w = f2bf(vv[3]);
                *(ushort4*)(HoutF + off) = pk;
            } else {
                int orow = ot * 32 + 8 * w + 4 * h;
                #pragma unroll
                for (int j = 0; j < 4; ++j)
                    if (orow + j < Oreal) outF[(size_t)b * Oreal + orow + j] = vv[j];
            }
        }
        __syncthreads();   // red WAR across grid-stride iterations
    }
}

#define PFNN_PARAMS \
    const float* __restrict__ x, \
    const float* __restrict__ W0, const float* __restrict__ W1, const float* __restrict__ W2, \
    const float* __restrict__ bias0, const float* __restrict__ bias1, const float* __restrict__ bias2, \
    float* __restrict__ outF, float* __restrict__ coef, \
    unsigned short* __restrict__ xf, \
    unsigned short* __restrict__ H1f, unsigned short* __restrict__ H2f, \
    unsigned short* __restrict__ Wf0, unsigned short* __restrict__ Wf1, unsigned short* __restrict__ Wf2

__global__ void __launch_bounds__(256, 2) pfnn_fused(PFNN_PARAMS, unsigned* bar, unsigned nblk) {
    __shared__ union { float s[32 * 66]; float red[4 * 1024]; } u;   // 16 KB
    const int bid = blockIdx.x, tid = threadIdx.x, gdim = gridDim.x;
    unsigned* cnt = bar;
    unsigned* gen = bar + 16;   // separate cache lines

    for (int un = bid; un < 200; un += gdim)
        phaseA_unit(un, tid, u.s, x, W0, W1, W2, bias0, bias1, bias2,
                    coef, xf, H1f, H2f, Wf0, Wf1, Wf2);
    grid_barrier(cnt, gen, nblk);
    layer_phase<true,  true,  384, 512>(Wf0, xf,  coef, H1f, nullptr, 512, u.red, bid, tid, gdim);
    grid_barrier(cnt, gen, nblk);
    layer_phase<true,  true,  576, 512>(Wf1, H1f, coef, H2f, nullptr, 512, u.red, bid, tid, gdim);
    grid_barrier(cnt, gen, nblk);
    layer_phase<false, false, 576, 320>(Wf2, H2f, coef, nullptr, outF, 311, u.red, bid, tid, gdim);
}

// -------- fallback: plain dispatches of the same verified bodies --------
__global__ void __launch_bounds__(256) phaseA_kernel(PFNN_PARAMS) {
    __shared__ float s[32 * 66];
    for (int un = blockIdx.x; un < 200; un += gridDim.x)
        phaseA_unit(un, threadIdx.x, s, x, W0, W1, W2, bias0, bias1, bias2,
                    coef, xf, H1f, H2f, Wf0, Wf1, Wf2);
    (void)outF;
}
__global__ void __launch_bounds__(256, 2) layer0_kernel(PFNN_PARAMS) {
    __shared__ float red[4 * 1024];
    layer_phase<true, true, 384, 512>(Wf0, xf, coef, H1f, nullptr, 512, red, blockIdx.x, threadIdx.x, gridDim.x);
    (void)outF;
}
__global__ void __launch_bounds__(256, 2) layer1_kernel(PFNN_PARAMS) {
    __shared__ float red[4 * 1024];
    layer_phase<true, true, 576, 512>(Wf1, H1f, coef, H2f, nullptr, 512, red, blockIdx.x, threadIdx.x, gridDim.x);
    (void)outF;
}
__global__ void __launch_bounds__(256, 2) layer2_kernel(PFNN_PARAMS) {
    __shared__ float red[4 * 1024];
    layer_phase<false, false, 576, 320>(Wf2, H2f, coef, nullptr, outF, 311, red, blockIdx.x, threadIdx.x, gridDim.x);
}

extern "C" void kernel_launch(void* const* d_in, const int* in_sizes, int n_in,
                              void* d_out, int out_size, void* d_ws, size_t ws_size,
                              hipStream_t stream) {
    (void)in_sizes; (void)n_in; (void)out_size; (void)ws_size;
    const float* x  = (const float*)d_in[0];
    const float* W0 = (const float*)d_in[1];
    const float* W1 = (const float*)d_in[2];
    const float* W2 = (const float*)d_in[3];
    const float* b0 = (const float*)d_in[4];
    const float* b1 = (const float*)d_in[5];
    const float* b2 = (const float*)d_in[6];
    float* out = (float*)d_out;

    char* wsb = (char*)d_ws;
    float*          coef = (float*)(wsb + 0);                  //   16384 B
    unsigned short* xf   = (unsigned short*)(wsb + 16384);     // (32,24,64,8)
    unsigned short* H1f  = (unsigned short*)(wsb + 802816);    // (32,36,64,8)
    unsigned short* H2f  = (unsigned short*)(wsb + 1982464);   // (32,36,64,8)
    unsigned short* Wf0  = (unsigned short*)(wsb + 3162112);   // (4,16,24,64,8)
    unsigned short* Wf1  = (unsigned short*)(wsb + 4734976);   // (4,16,36,64,8)
    unsigned short* Wf2  = (unsigned short*)(wsb + 7094272);   // (4,10,36,64,8)
    unsigned*       bar  = (unsigned*)(wsb + 8568832);         // 128 B barrier state

    int maxb = 0;
    hipError_t qe = hipOccupancyMaxActiveBlocksPerMultiprocessor(
        &maxb, (const void*)pfnn_fused, 256, 0);
    unsigned grid = 256;
    if (qe == hipSuccess && maxb >= 2) grid = 512;

    hipMemsetAsync(bar, 0, 128, stream);

    void* args[] = {
        (void*)&x, (void*)&W0, (void*)&W1, (void*)&W2,
        (void*)&b0, (void*)&b1, (void*)&b2, (void*)&out,
        (void*)&coef, (void*)&xf, (void*)&H1f, (void*)&H2f,
        (void*)&Wf0, (void*)&Wf1, (void*)&Wf2,
        (void*)&bar, (void*)&grid
    };
    hipError_t e = hipLaunchCooperativeKernel((const void*)pfnn_fused,
                                              dim3(grid), dim3(256), args, 0, stream);
    if (e != hipSuccess) {
        (void)hipGetLastError();
        phaseA_kernel<<<dim3(200), dim3(256), 0, stream>>>(x, W0, W1, W2, b0, b1, b2, out, coef, xf, H1f, H2f, Wf0, Wf1, Wf2);
        layer0_kernel<<<dim3(512), dim3(256), 0, stream>>>(x, W0, W1, W2, b0, b1, b2, out, coef, xf, H1f, H2f, Wf0, Wf1, Wf2);
        layer1_kernel<<<dim3(512), dim3(256), 0, stream>>>(x, W0, W1, W2, b0, b1, b2, out, coef, xf, H1f, H2f, Wf0, Wf1, Wf2);
        layer2_kernel<<<dim3(320), dim3(256), 0, stream>>>(x, W0, W1, W2, b0, b1, b2, out, coef, xf, H1f, H2f, Wf0, Wf1, Wf2);
    }
}

// Round 9
// 153.476 us; speedup vs baseline: 2.1051x; 2.1051x over previous
//
#include <hip/hip_runtime.h>
#include <math.h>

typedef short bf16x8 __attribute__((ext_vector_type(8)));
typedef float f32x16 __attribute__((ext_vector_type(16)));

__device__ __forceinline__ unsigned short f2bf(float f) {
    union { float f; unsigned u; } x; x.f = f;
    unsigned r = x.u + 0x7FFFu + ((x.u >> 16) & 1u);
    return (unsigned short)(r >> 16);
}

// ---- dataflow sync helpers (agent scope = cross-XCD; protocol HW-verified r8) ----
__device__ __forceinline__ void sig(unsigned* c) {
    __syncthreads();                     // all block stores drained (vmcnt0 at barrier)
    if (threadIdx.x == 0)
        __hip_atomic_fetch_add(c, 1u, __ATOMIC_RELEASE, __HIP_MEMORY_SCOPE_AGENT);
}
__device__ __forceinline__ void wait2(unsigned* c1, unsigned t1, unsigned* c2, unsigned t2) {
    if (threadIdx.x == 0) {
        while (__hip_atomic_load(c1, __ATOMIC_RELAXED, __HIP_MEMORY_SCOPE_AGENT) < t1)
            __builtin_amdgcn_s_sleep(1);
        while (__hip_atomic_load(c2, __ATOMIC_RELAXED, __HIP_MEMORY_SCOPE_AGENT) < t2)
            __builtin_amdgcn_s_sleep(1);
        (void)__hip_atomic_load(c1, __ATOMIC_ACQUIRE, __HIP_MEMORY_SCOPE_AGENT); // one inv
    }
    __syncthreads();
}

// ---- Transpose one 32-row fp32 tile into frag-major bf16 (round-7 verified) ----
template<int NKS_T>
__device__ void transpose_tile(const float* __restrict__ W, const float* __restrict__ bias,
                               int rowbase, int rowlimit, int Kreal, int ldsrc,
                               unsigned short* __restrict__ dst, float* s, int tid)
{
    constexpr int NCHK = NKS_T / 4;
    const int r = tid >> 3, l = tid & 7;
    const int ks_l = tid >> 6, lane = tid & 63;
    const int m = lane & 31, h = lane >> 5;
    for (int kc = 0; kc < NCHK; ++kc) {
        {
            int kb = kc * 64 + l * 8;
            const bool rv = r < rowlimit;
            const float* src = W + (size_t)(rowbase + r) * ldsrc + kb;
            float v[8];
            if (rv && kb + 7 < Kreal) {
                #pragma unroll
                for (int i = 0; i < 8; ++i) v[i] = src[i];
            } else {
                #pragma unroll
                for (int i = 0; i < 8; ++i) {
                    int k = kb + i;
                    v[i] = (rv && k < Kreal) ? src[i]
                         : ((rv && k == Kreal) ? (bias ? bias[rowbase + r] : 1.0f) : 0.f);
                }
            }
            #pragma unroll
            for (int i = 0; i < 8; ++i) s[r * 66 + l * 8 + i] = v[i];
        }
        __syncthreads();
        {
            bf16x8 pk;
            #pragma unroll
            for (int j = 0; j < 8; ++j)
                pk[j] = (short)f2bf(s[m * 66 + ks_l * 16 + h * 8 + j]);
            *(bf16x8*)(dst + ((size_t)(kc * 4 + ks_l) * 64 + lane) * 8) = pk;
        }
        __syncthreads();
    }
}

// ---- Phase A unit u in [0,200) (round-7 verified bodies) ----
// u<32: xf tile bt=u (+coef +H1/H2 tails); 32..95: W0(n,ot); 96..159: W1; 160..199: W2.
__device__ void phaseA_unit(
    int u, int tid, float* s,
    const float* __restrict__ x,
    const float* __restrict__ W0, const float* __restrict__ W1, const float* __restrict__ W2,
    const float* __restrict__ bias0, const float* __restrict__ bias1, const float* __restrict__ bias2,
    float* __restrict__ coef, unsigned short* __restrict__ xf,
    unsigned short* __restrict__ H1f, unsigned short* __restrict__ H2f,
    unsigned short* __restrict__ Wf0, unsigned short* __restrict__ Wf1, unsigned short* __restrict__ Wf2)
{
    if (u < 32) {
        const int bt = u;
        if (tid < 32) {
            int b = bt * 32 + tid;
            float phase = x[(size_t)b * 343 + 342];
            float ps = 4.0f * phase;
            int k1 = (int)ps;
            float mu = ps - (float)k1;
            k1 &= 3;
            float mu2 = mu * mu, mu3 = mu2 * mu;
            float c0 = -0.5f * mu3 +        mu2 - 0.5f * mu;
            float c1 =  1.5f * mu3 - 2.5f * mu2 + 1.0f;
            float c2 = -1.5f * mu3 + 2.0f * mu2 + 0.5f * mu;
            float c3 =  0.5f * mu3 - 0.5f * mu2;
            float cc[4];
            cc[(k1 + 3) & 3] = c0;
            cc[k1]           = c1;
            cc[(k1 + 1) & 3] = c2;
            cc[(k1 + 2) & 3] = c3;
            *(float4*)(coef + b * 4) = make_float4(cc[0], cc[1], cc[2], cc[3]);
        }
        {
            int kk = tid >> 6, lane = tid & 63;
            size_t off = ((size_t)(bt * 36 + 32 + kk) * 64 + lane) * 8;
            bf16x8 v;
            #pragma unroll
            for (int j = 0; j < 8; ++j)
                v[j] = (short)((kk == 0 && (lane >> 5) == 0 && j == 0) ? 0x3F80 : 0);
            *(bf16x8*)(H1f + off) = v;
            *(bf16x8*)(H2f + off) = v;
        }
        transpose_tile<24>(x, nullptr, bt * 32, 32, 342, 343,
                           xf + (size_t)bt * 24 * 512, s, tid);
    } else if (u < 96) {
        int idx = u - 32, n = idx >> 4, ot = idx & 15;
        transpose_tile<24>(W0, bias0, n * 512 + ot * 32, 32, 342, 342,
                           Wf0 + (size_t)(n * 16 + ot) * 24 * 512, s, tid);
    } else if (u < 160) {
        int idx = u - 96, n = idx >> 4, ot = idx & 15;
        transpose_tile<36>(W1, bias1, n * 512 + ot * 32, 32, 512, 512,
                           Wf1 + (size_t)(n * 16 + ot) * 36 * 512, s, tid);
    } else {
        int idx = u - 160, n = idx / 10, ot = idx % 10;
        int rl = 311 - ot * 32; if (rl > 32) rl = 32;
        transpose_tile<36>(W2, bias2, n * 311 + ot * 32, rl, 512, 512,
                           Wf2 + (size_t)(n * 10 + ot) * 36 * 512, s, tid);
    }
}

// ---- One layer tile (round-7 verified body): 32o x 32b x 4 banks, 4-wave split-K ----
template<bool ELU, bool OUT_BF16, int KP, int OPAD>
__device__ __forceinline__ void layer_tile(
    const unsigned short* __restrict__ Wf,
    const unsigned short* __restrict__ Hf,
    const float* __restrict__ coef,
    unsigned short* __restrict__ HoutF,
    float* __restrict__ outF, int Oreal,
    float* red, int t, int tid)
{
    constexpr int NOT = OPAD / 32, NKS = KP / 16, KSQ = NKS / 4;
    constexpr int CH = 3, NC2 = KSQ / CH;
    const int lane = tid & 63, w = tid >> 6;
    const int m = lane & 31, h = lane >> 5;
    const size_t nstr = (size_t)NOT * NKS * 512;

    const int ot = t >> 5, bt = t & 31;
    const unsigned short* wbase = Wf + ((size_t)ot * NKS + w * KSQ) * 512 + (size_t)lane * 8;
    const unsigned short* bbase = Hf + ((size_t)bt * NKS + w * KSQ) * 512 + (size_t)lane * 8;

    f32x16 acc0 = {}, acc1 = {}, acc2 = {}, acc3 = {};
    bf16x8 Ab[2][CH][4], Bb[2][CH];

    #pragma unroll
    for (int sI = 0; sI < CH; ++sI) {
        Bb[0][sI] = *(const bf16x8*)(bbase + (size_t)sI * 512);
        #pragma unroll
        for (int n = 0; n < 4; ++n)
            Ab[0][sI][n] = *(const bf16x8*)(wbase + (size_t)n * nstr + (size_t)sI * 512);
    }
    #pragma unroll
    for (int c = 0; c < NC2; ++c) {
        const int cur = c & 1;
        if (c + 1 < NC2) {
            const int nxt = cur ^ 1;
            #pragma unroll
            for (int sI = 0; sI < CH; ++sI) {
                int st = (c + 1) * CH + sI;
                Bb[nxt][sI] = *(const bf16x8*)(bbase + (size_t)st * 512);
                #pragma unroll
                for (int n = 0; n < 4; ++n)
                    Ab[nxt][sI][n] = *(const bf16x8*)(wbase + (size_t)n * nstr + (size_t)st * 512);
            }
        }
        #pragma unroll
        for (int sI = 0; sI < CH; ++sI) {
            acc0 = __builtin_amdgcn_mfma_f32_32x32x16_bf16(Ab[cur][sI][0], Bb[cur][sI], acc0, 0, 0, 0);
            acc1 = __builtin_amdgcn_mfma_f32_32x32x16_bf16(Ab[cur][sI][1], Bb[cur][sI], acc1, 0, 0, 0);
            acc2 = __builtin_amdgcn_mfma_f32_32x32x16_bf16(Ab[cur][sI][2], Bb[cur][sI], acc2, 0, 0, 0);
            acc3 = __builtin_amdgcn_mfma_f32_32x32x16_bf16(Ab[cur][sI][3], Bb[cur][sI], acc3, 0, 0, 0);
        }
    }

    const int b = bt * 32 + m;
    float4 cf = *(const float4*)(coef + b * 4);
    #pragma unroll
    for (int g = 0; g < 4; ++g)
        #pragma unroll
        for (int j = 0; j < 4; ++j) {
            int rI = g * 4 + j;
            float v = cf.x * acc0[rI] + cf.y * acc1[rI] + cf.z * acc2[rI] + cf.w * acc3[rI];
            red[w * 1024 + (8 * g + 4 * h + j) * 32 + m] = v;
        }
    __syncthreads();
    {
        float vv[4];
        #pragma unroll
        for (int j = 0; j < 4; ++j) {
            int row = 8 * w + 4 * h + j;
            float v = red[row * 32 + m] + red[1024 + row * 32 + m]
                    + red[2048 + row * 32 + m] + red[3072 + row * 32 + m];
            if (ELU) v = (v > 0.f) ? v : expm1f(v);
            vv[j] = v;
        }
        if (OUT_BF16) {
            size_t off = (((size_t)bt * 36 + ot * 2 + (w >> 1)) * 64
                          + (w & 1) * 32 + m) * 8 + 4 * h;
            ushort4 pk;
            pk.x = f2bf(vv[0]); pk.y = f2bf(vv[1]); pk.z = f2bf(vv[2]); pk.w = f2bf(vv[3]);
            *(ushort4*)(HoutF + off) = pk;
        } else {
            int orow = ot * 32 + 8 * w + 4 * h;
            #pragma unroll
            for (int j = 0; j < 4; ++j)
                if (orow + j < Oreal) outF[(size_t)b * Oreal + orow + j] = vv[j];
        }
    }
}

#define PFNN_PARAMS \
    const float* __restrict__ x, \
    const float* __restrict__ W0, const float* __restrict__ W1, const float* __restrict__ W2, \
    const float* __restrict__ bias0, const float* __restrict__ bias1, const float* __restrict__ bias2, \
    float* __restrict__ outF, float* __restrict__ coef, \
    unsigned short* __restrict__ xf, \
    unsigned short* __restrict__ H1f, unsigned short* __restrict__ H2f, \
    unsigned short* __restrict__ Wf0, unsigned short* __restrict__ Wf1, unsigned short* __restrict__ Wf2

// Dataflow-fused persistent kernel. Flag lines (64B apart), zeroed pre-launch:
//   cntW0[16]@0, cntW1[16]@256, cntW2[10]@512, cntX[32]@768, cntH1[32]@1280, cntH2[32]@1792
__global__ void __launch_bounds__(256, 2) pfnn_fused(PFNN_PARAMS, unsigned* flags) {
    __shared__ union { float s[32 * 66]; float red[4 * 1024]; } u;   // 16 KB
    const int b = blockIdx.x, tid = threadIdx.x;
    unsigned* cntW0 = flags;
    unsigned* cntW1 = flags + 256;
    unsigned* cntW2 = flags + 512;
    unsigned* cntX  = flags + 768;
    unsigned* cntH1 = flags + 1280;
    unsigned* cntH2 = flags + 1792;

    // ---- phase A (blocks 0..199, one unit each) ----
    if (b < 200) {
        phaseA_unit(b, tid, u.s, x, W0, W1, W2, bias0, bias1, bias2,
                    coef, xf, H1f, H2f, Wf0, Wf1, Wf2);
        if (b < 32) {                 // xf + coef + H1/H2 tails for bt=b
            sig(cntX  + b * 16);
            sig(cntH1 + b * 16);
            sig(cntH2 + b * 16);
        } else if (b < 96)  sig(cntW0 + ((b - 32) & 15) * 16);
        else if (b < 160)   sig(cntW1 + ((b - 96) & 15) * 16);
        else                sig(cntW2 + ((b - 160) % 10) * 16);
    }

    // ---- layer 0: tile b ----
    {
        const int ot = b >> 5, bt = b & 31;
        wait2(cntW0 + ot * 16, 4u, cntX + bt * 16, 1u);
        layer_tile<true, true, 384, 512>(Wf0, xf, coef, H1f, nullptr, 512, u.red, b, tid);
        sig(cntH1 + bt * 16);
    }
    // ---- layer 1: tile b ----
    {
        const int ot = b >> 5, bt = b & 31;
        wait2(cntW1 + ot * 16, 4u, cntH1 + bt * 16, 17u);   // 16 tiles + 1 tail unit
        layer_tile<true, true, 576, 512>(Wf1, H1f, coef, H2f, nullptr, 512, u.red, b, tid);
        sig(cntH2 + bt * 16);
    }
    // ---- layer 2: tile b (320 tiles) ----
    if (b < 320) {
        const int ot = b >> 5, bt = b & 31;
        wait2(cntW2 + ot * 16, 4u, cntH2 + bt * 16, 17u);
        layer_tile<false, false, 576, 320>(Wf2, H2f, coef, nullptr, outF, 311, u.red, b, tid);
    }
}

// -------- fallback: round-7 4-dispatch path (proven 94.9 us) --------
__global__ void __launch_bounds__(256) phaseA_kernel(PFNN_PARAMS) {
    __shared__ float s[32 * 66];
    for (int un = blockIdx.x; un < 200; un += gridDim.x)
        phaseA_unit(un, threadIdx.x, s, x, W0, W1, W2, bias0, bias1, bias2,
                    coef, xf, H1f, H2f, Wf0, Wf1, Wf2);
    (void)outF;
}
__global__ void __launch_bounds__(256, 2) layer0_kernel(PFNN_PARAMS) {
    __shared__ float red[4 * 1024];
    layer_tile<true, true, 384, 512>(Wf0, xf, coef, H1f, nullptr, 512, red, blockIdx.x, threadIdx.x);
    (void)outF;
}
__global__ void __launch_bounds__(256, 2) layer1_kernel(PFNN_PARAMS) {
    __shared__ float red[4 * 1024];
    layer_tile<true, true, 576, 512>(Wf1, H1f, coef, H2f, nullptr, 512, red, blockIdx.x, threadIdx.x);
    (void)outF;
}
__global__ void __launch_bounds__(256, 2) layer2_kernel(PFNN_PARAMS) {
    __shared__ float red[4 * 1024];
    layer_tile<false, false, 576, 320>(Wf2, H2f, coef, nullptr, outF, 311, red, blockIdx.x, threadIdx.x);
}

extern "C" void kernel_launch(void* const* d_in, const int* in_sizes, int n_in,
                              void* d_out, int out_size, void* d_ws, size_t ws_size,
                              hipStream_t stream) {
    (void)in_sizes; (void)n_in; (void)out_size; (void)ws_size;
    const float* x  = (const float*)d_in[0];
    const float* W0 = (const float*)d_in[1];
    const float* W1 = (const float*)d_in[2];
    const float* W2 = (const float*)d_in[3];
    const float* b0 = (const float*)d_in[4];
    const float* b1 = (const float*)d_in[5];
    const float* b2 = (const float*)d_in[6];
    float* out = (float*)d_out;

    char* wsb = (char*)d_ws;
    float*          coef  = (float*)(wsb + 0);
    unsigned short* xf    = (unsigned short*)(wsb + 16384);
    unsigned short* H1f   = (unsigned short*)(wsb + 802816);
    unsigned short* H2f   = (unsigned short*)(wsb + 1982464);
    unsigned short* Wf0   = (unsigned short*)(wsb + 3162112);
    unsigned short* Wf1   = (unsigned short*)(wsb + 4734976);
    unsigned short* Wf2   = (unsigned short*)(wsb + 7094272);
    unsigned*       flags = (unsigned*)(wsb + 8568832);

    int maxb = 0;
    hipError_t qe = hipOccupancyMaxActiveBlocksPerMultiprocessor(
        &maxb, (const void*)pfnn_fused, 256, 0);

    if (qe == hipSuccess && maxb >= 2) {
        hipMemsetAsync(flags, 0, 12288, stream);
        void* args[] = {
            (void*)&x, (void*)&W0, (void*)&W1, (void*)&W2,
            (void*)&b0, (void*)&b1, (void*)&b2, (void*)&out,
            (void*)&coef, (void*)&xf, (void*)&H1f, (void*)&H2f,
            (void*)&Wf0, (void*)&Wf1, (void*)&Wf2, (void*)&flags
        };
        hipError_t e = hipLaunchCooperativeKernel((const void*)pfnn_fused,
                                                  dim3(512), dim3(256), args, 0, stream);
        if (e == hipSuccess) return;
        (void)hipGetLastError();
    }
    phaseA_kernel<<<dim3(200), dim3(256), 0, stream>>>(x, W0, W1, W2, b0, b1, b2, out, coef, xf, H1f, H2f, Wf0, Wf1, Wf2);
    layer0_kernel<<<dim3(512), dim3(256), 0, stream>>>(x, W0, W1, W2, b0, b1, b2, out, coef, xf, H1f, H2f, Wf0, Wf1, Wf2);
    layer1_kernel<<<dim3(512), dim3(256), 0, stream>>>(x, W0, W1, W2, b0, b1, b2, out, coef, xf, H1f, H2f, Wf0, Wf1, Wf2);
    layer2_kernel<<<dim3(320), dim3(256), 0, stream>>>(x, W0, W1, W2, b0, b1, b2, out, coef, xf, H1f, H2f, Wf0, Wf1, Wf2);
}

// Round 10
// 100.126 us; speedup vs baseline: 3.2268x; 1.5328x over previous
//
#include <hip/hip_runtime.h>
#include <math.h>

typedef short bf16x8 __attribute__((ext_vector_type(8)));
typedef float f32x16 __attribute__((ext_vector_type(16)));
typedef float f32x4  __attribute__((ext_vector_type(4)));

__device__ __forceinline__ unsigned short f2bf(float f) {
    union { float f; unsigned u; } x; x.f = f;
    unsigned r = x.u + 0x7FFFu + ((x.u >> 16) & 1u);
    return (unsigned short)(r >> 16);
}

// ---- dataflow sync (agent scope, HW-verified r8/r9) ----
__device__ __forceinline__ void sig(unsigned* c) {
    __syncthreads();                     // block stores drained (vmcnt 0 at barrier)
    if (threadIdx.x == 0)
        __hip_atomic_fetch_add(c, 1u, __ATOMIC_RELEASE, __HIP_MEMORY_SCOPE_AGENT);
}
__device__ __forceinline__ void sig3(unsigned* a, unsigned* b, unsigned* c) {
    __syncthreads();
    if (threadIdx.x == 0) {
        __hip_atomic_fetch_add(a, 1u, __ATOMIC_RELEASE, __HIP_MEMORY_SCOPE_AGENT);
        __hip_atomic_fetch_add(b, 1u, __ATOMIC_RELEASE, __HIP_MEMORY_SCOPE_AGENT);
        __hip_atomic_fetch_add(c, 1u, __ATOMIC_RELEASE, __HIP_MEMORY_SCOPE_AGENT);
    }
}
__device__ __forceinline__ void wait2(unsigned* c1, unsigned t1, unsigned* c2, unsigned t2) {
    if (threadIdx.x == 0) {
        while (__hip_atomic_load(c1, __ATOMIC_RELAXED, __HIP_MEMORY_SCOPE_AGENT) < t1)
            __builtin_amdgcn_s_sleep(1);
        while (__hip_atomic_load(c2, __ATOMIC_RELAXED, __HIP_MEMORY_SCOPE_AGENT) < t2)
            __builtin_amdgcn_s_sleep(1);
        (void)__hip_atomic_load(c1, __ATOMIC_ACQUIRE, __HIP_MEMORY_SCOPE_AGENT); // one inv
    }
    __syncthreads();
}

// ---- masked 8-float chunk load (row r of tile; bias fold at k==Kreal) ----
__device__ __forceinline__ void load8(const float* __restrict__ W, const float* __restrict__ bias,
                                      int rowbase, int rowlimit, int Kreal, int ldsrc,
                                      int r, int kb, float v[8])
{
    const bool rv = r < rowlimit;
    const float* src = W + (size_t)(rowbase + r) * ldsrc + kb;
    if (rv && kb + 7 < Kreal) {
        #pragma unroll
        for (int i = 0; i < 8; ++i) v[i] = src[i];
    } else {
        #pragma unroll
        for (int i = 0; i < 8; ++i) {
            int k = kb + i;
            v[i] = (rv && k < Kreal) ? src[i]
                 : ((rv && k == Kreal) ? (bias ? bias[rowbase + r] : 1.0f) : 0.f);
        }
    }
}

// ---- Transpose one 32-row fp32 tile into frag-major bf16 (r7-verified layout) ----
// Register-double-buffered chunk loads: chunk kc+1 issued before converting kc.
template<int NKS_T>
__device__ void transpose_tile(const float* __restrict__ W, const float* __restrict__ bias,
                               int rowbase, int rowlimit, int Kreal, int ldsrc,
                               unsigned short* __restrict__ dst, float* s, int tid)
{
    constexpr int NCHK = NKS_T / 4;
    const int r = tid >> 3, l = tid & 7;
    const int ks_l = tid >> 6, lane = tid & 63;
    const int m = lane & 31, h = lane >> 5;

    float cur[8], nxt[8];
    load8(W, bias, rowbase, rowlimit, Kreal, ldsrc, r, 0 * 64 + l * 8, cur);
    for (int kc = 0; kc < NCHK; ++kc) {
        if (kc + 1 < NCHK)   // issue next global load early; overlaps LDS+convert
            load8(W, bias, rowbase, rowlimit, Kreal, ldsrc, r, (kc + 1) * 64 + l * 8, nxt);
        #pragma unroll
        for (int i = 0; i < 8; ++i) s[r * 66 + l * 8 + i] = cur[i];
        __syncthreads();
        {
            bf16x8 pk;
            #pragma unroll
            for (int j = 0; j < 8; ++j)
                pk[j] = (short)f2bf(s[m * 66 + ks_l * 16 + h * 8 + j]);
            __builtin_nontemporal_store(pk,
                (bf16x8*)(dst + ((size_t)(kc * 4 + ks_l) * 64 + lane) * 8));
        }
        __syncthreads();
        #pragma unroll
        for (int i = 0; i < 8; ++i) cur[i] = nxt[i];
    }
}

// ---- Phase A unit u in [0,200) (r7-verified bodies) ----
__device__ void phaseA_unit(
    int u, int tid, float* s,
    const float* __restrict__ x,
    const float* __restrict__ W0, const float* __restrict__ W1, const float* __restrict__ W2,
    const float* __restrict__ bias0, const float* __restrict__ bias1, const float* __restrict__ bias2,
    float* __restrict__ coef, unsigned short* __restrict__ xf,
    unsigned short* __restrict__ H1f, unsigned short* __restrict__ H2f,
    unsigned short* __restrict__ Wf0, unsigned short* __restrict__ Wf1, unsigned short* __restrict__ Wf2)
{
    if (u < 32) {
        const int bt = u;
        if (tid < 32) {
            int b = bt * 32 + tid;
            float phase = x[(size_t)b * 343 + 342];
            float ps = 4.0f * phase;
            int k1 = (int)ps;
            float mu = ps - (float)k1;
            k1 &= 3;
            float mu2 = mu * mu, mu3 = mu2 * mu;
            float c0 = -0.5f * mu3 +        mu2 - 0.5f * mu;
            float c1 =  1.5f * mu3 - 2.5f * mu2 + 1.0f;
            float c2 = -1.5f * mu3 + 2.0f * mu2 + 0.5f * mu;
            float c3 =  0.5f * mu3 - 0.5f * mu2;
            float cc[4];
            cc[(k1 + 3) & 3] = c0;
            cc[k1]           = c1;
            cc[(k1 + 1) & 3] = c2;
            cc[(k1 + 2) & 3] = c3;
            f32x4 cv; cv[0] = cc[0]; cv[1] = cc[1]; cv[2] = cc[2]; cv[3] = cc[3];
            __builtin_nontemporal_store(cv, (f32x4*)(coef + b * 4));
        }
        {
            int kk = tid >> 6, lane = tid & 63;
            size_t off = ((size_t)(bt * 36 + 32 + kk) * 64 + lane) * 8;
            bf16x8 v;
            #pragma unroll
            for (int j = 0; j < 8; ++j)
                v[j] = (short)((kk == 0 && (lane >> 5) == 0 && j == 0) ? 0x3F80 : 0);
            __builtin_nontemporal_store(v, (bf16x8*)(H1f + off));
            __builtin_nontemporal_store(v, (bf16x8*)(H2f + off));
        }
        transpose_tile<24>(x, nullptr, bt * 32, 32, 342, 343,
                           xf + (size_t)bt * 24 * 512, s, tid);
    } else if (u < 96) {
        int idx = u - 32, n = idx >> 4, ot = idx & 15;
        transpose_tile<24>(W0, bias0, n * 512 + ot * 32, 32, 342, 342,
                           Wf0 + (size_t)(n * 16 + ot) * 24 * 512, s, tid);
    } else if (u < 160) {
        int idx = u - 96, n = idx >> 4, ot = idx & 15;
        transpose_tile<36>(W1, bias1, n * 512 + ot * 32, 32, 512, 512,
                           Wf1 + (size_t)(n * 16 + ot) * 36 * 512, s, tid);
    } else {
        int idx = u - 160, n = idx / 10, ot = idx % 10;
        int rl = 311 - ot * 32; if (rl > 32) rl = 32;
        transpose_tile<36>(W2, bias2, n * 311 + ot * 32, rl, 512, 512,
                           Wf2 + (size_t)(n * 10 + ot) * 36 * 512, s, tid);
    }
}

// ---- One layer tile (r7-verified): 32o x 32b x 4 banks, 4-wave split-K ----
template<bool ELU, bool OUT_BF16, int KP, int OPAD>
__device__ __forceinline__ void layer_tile(
    const unsigned short* __restrict__ Wf,
    const unsigned short* __restrict__ Hf,
    const float* __restrict__ coef,
    unsigned short* __restrict__ HoutF,
    float* __restrict__ outF, int Oreal,
    float* red, int t, int tid)
{
    constexpr int NOT = OPAD / 32, NKS = KP / 16, KSQ = NKS / 4;
    constexpr int CH = 3, NC2 = KSQ / CH;
    const int lane = tid & 63, w = tid >> 6;
    const int m = lane & 31, h = lane >> 5;
    const size_t nstr = (size_t)NOT * NKS * 512;

    const int ot = t >> 5, bt = t & 31;
    const unsigned short* wbase = Wf + ((size_t)ot * NKS + w * KSQ) * 512 + (size_t)lane * 8;
    const unsigned short* bbase = Hf + ((size_t)bt * NKS + w * KSQ) * 512 + (size_t)lane * 8;

    f32x16 acc0 = {}, acc1 = {}, acc2 = {}, acc3 = {};
    bf16x8 Ab[2][CH][4], Bb[2][CH];

    #pragma unroll
    for (int sI = 0; sI < CH; ++sI) {
        Bb[0][sI] = *(const bf16x8*)(bbase + (size_t)sI * 512);
        #pragma unroll
        for (int n = 0; n < 4; ++n)
            Ab[0][sI][n] = *(const bf16x8*)(wbase + (size_t)n * nstr + (size_t)sI * 512);
    }
    #pragma unroll
    for (int c = 0; c < NC2; ++c) {
        const int cur = c & 1;
        if (c + 1 < NC2) {
            const int nxt = cur ^ 1;
            #pragma unroll
            for (int sI = 0; sI < CH; ++sI) {
                int st = (c + 1) * CH + sI;
                Bb[nxt][sI] = *(const bf16x8*)(bbase + (size_t)st * 512);
                #pragma unroll
                for (int n = 0; n < 4; ++n)
                    Ab[nxt][sI][n] = *(const bf16x8*)(wbase + (size_t)n * nstr + (size_t)st * 512);
            }
        }
        #pragma unroll
        for (int sI = 0; sI < CH; ++sI) {
            acc0 = __builtin_amdgcn_mfma_f32_32x32x16_bf16(Ab[cur][sI][0], Bb[cur][sI], acc0, 0, 0, 0);
            acc1 = __builtin_amdgcn_mfma_f32_32x32x16_bf16(Ab[cur][sI][1], Bb[cur][sI], acc1, 0, 0, 0);
            acc2 = __builtin_amdgcn_mfma_f32_32x32x16_bf16(Ab[cur][sI][2], Bb[cur][sI], acc2, 0, 0, 0);
            acc3 = __builtin_amdgcn_mfma_f32_32x32x16_bf16(Ab[cur][sI][3], Bb[cur][sI], acc3, 0, 0, 0);
        }
    }

    const int b = bt * 32 + m;
    float4 cf = *(const float4*)(coef + b * 4);
    #pragma unroll
    for (int g = 0; g < 4; ++g)
        #pragma unroll
        for (int j = 0; j < 4; ++j) {
            int rI = g * 4 + j;
            float v = cf.x * acc0[rI] + cf.y * acc1[rI] + cf.z * acc2[rI] + cf.w * acc3[rI];
            red[w * 1024 + (8 * g + 4 * h + j) * 32 + m] = v;
        }
    __syncthreads();
    {
        float vv[4];
        #pragma unroll
        for (int j = 0; j < 4; ++j) {
            int row = 8 * w + 4 * h + j;
            float v = red[row * 32 + m] + red[1024 + row * 32 + m]
                    + red[2048 + row * 32 + m] + red[3072 + row * 32 + m];
            if (ELU) v = (v > 0.f) ? v : expm1f(v);
            vv[j] = v;
        }
        if (OUT_BF16) {
            size_t off = (((size_t)bt * 36 + ot * 2 + (w >> 1)) * 64
                          + (w & 1) * 32 + m) * 8 + 4 * h;
            ushort4 pk;
            pk.x = f2bf(vv[0]); pk.y = f2bf(vv[1]); pk.z = f2bf(vv[2]); pk.w = f2bf(vv[3]);
            __builtin_nontemporal_store(*(unsigned long long*)&pk,
                                        (unsigned long long*)(HoutF + off));
        } else {
            int orow = ot * 32 + 8 * w + 4 * h;
            #pragma unroll
            for (int j = 0; j < 4; ++j)
                if (orow + j < Oreal) outF[(size_t)b * Oreal + orow + j] = vv[j];
        }
    }
}

#define PFNN_PARAMS \
    const float* __restrict__ x, \
    const float* __restrict__ W0, const float* __restrict__ W1, const float* __restrict__ W2, \
    const float* __restrict__ bias0, const float* __restrict__ bias1, const float* __restrict__ bias2, \
    float* __restrict__ outF, float* __restrict__ coef, \
    unsigned short* __restrict__ xf, \
    unsigned short* __restrict__ H1f, unsigned short* __restrict__ H2f, \
    unsigned short* __restrict__ Wf0, unsigned short* __restrict__ Wf1, unsigned short* __restrict__ Wf2

// tiny in-stream flag zeroing (avoids hipMemsetAsync graph node / engine-switch sync)
__global__ void __launch_bounds__(256) zero_flags(unsigned* flags) {
    #pragma unroll
    for (int i = 0; i < 12; ++i) flags[i * 256 + threadIdx.x] = 0u;
}

// Dataflow-fused persistent kernel (r9-verified). Flag lines 64B apart:
//   cntW0[16]@0, cntW1[16]@256, cntW2[10]@512, cntX[32]@768, cntH1[32]@1280, cntH2[32]@1792
__global__ void __launch_bounds__(256, 2) pfnn_fused(PFNN_PARAMS, unsigned* flags) {
    __shared__ union { float s[32 * 66]; float red[4 * 1024]; } u;   // 16 KB
    const int b = blockIdx.x, tid = threadIdx.x;
    unsigned* cntW0 = flags;
    unsigned* cntW1 = flags + 256;
    unsigned* cntW2 = flags + 512;
    unsigned* cntX  = flags + 768;
    unsigned* cntH1 = flags + 1280;
    unsigned* cntH2 = flags + 1792;

    if (b < 200) {
        phaseA_unit(b, tid, u.s, x, W0, W1, W2, bias0, bias1, bias2,
                    coef, xf, H1f, H2f, Wf0, Wf1, Wf2);
        if (b < 32)         sig3(cntX + b * 16, cntH1 + b * 16, cntH2 + b * 16);
        else if (b < 96)    sig(cntW0 + ((b - 32) & 15) * 16);
        else if (b < 160)   sig(cntW1 + ((b - 96) & 15) * 16);
        else                sig(cntW2 + ((b - 160) % 10) * 16);
    }

    {   // layer 0, tile b
        const int ot = b >> 5, bt = b & 31;
        wait2(cntW0 + ot * 16, 4u, cntX + bt * 16, 1u);
        layer_tile<true, true, 384, 512>(Wf0, xf, coef, H1f, nullptr, 512, u.red, b, tid);
        sig(cntH1 + bt * 16);
    }
    {   // layer 1, tile b
        const int ot = b >> 5, bt = b & 31;
        wait2(cntW1 + ot * 16, 4u, cntH1 + bt * 16, 17u);   // 16 tiles + 1 tail
        layer_tile<true, true, 576, 512>(Wf1, H1f, coef, H2f, nullptr, 512, u.red, b, tid);
        sig(cntH2 + bt * 16);
    }
    if (b < 320) {   // layer 2, tile b
        const int ot = b >> 5, bt = b & 31;
        wait2(cntW2 + ot * 16, 4u, cntH2 + bt * 16, 17u);
        layer_tile<false, false, 576, 320>(Wf2, H2f, coef, nullptr, outF, 311, u.red, b, tid);
    }
}

// -------- fallback: 4-dispatch path (r7-proven) --------
__global__ void __launch_bounds__(256) phaseA_kernel(PFNN_PARAMS) {
    __shared__ float s[32 * 66];
    for (int un = blockIdx.x; un < 200; un += gridDim.x)
        phaseA_unit(un, threadIdx.x, s, x, W0, W1, W2, bias0, bias1, bias2,
                    coef, xf, H1f, H2f, Wf0, Wf1, Wf2);
    (void)outF;
}
__global__ void __launch_bounds__(256, 2) layer0_kernel(PFNN_PARAMS) {
    __shared__ float red[4 * 1024];
    layer_tile<true, true, 384, 512>(Wf0, xf, coef, H1f, nullptr, 512, red, blockIdx.x, threadIdx.x);
    (void)outF;
}
__global__ void __launch_bounds__(256, 2) layer1_kernel(PFNN_PARAMS) {
    __shared__ float red[4 * 1024];
    layer_tile<true, true, 576, 512>(Wf1, H1f, coef, H2f, nullptr, 512, red, blockIdx.x, threadIdx.x);
    (void)outF;
}
__global__ void __launch_bounds__(256, 2) layer2_kernel(PFNN_PARAMS) {
    __shared__ float red[4 * 1024];
    layer_tile<false, false, 576, 320>(Wf2, H2f, coef, nullptr, outF, 311, red, blockIdx.x, threadIdx.x);
}

extern "C" void kernel_launch(void* const* d_in, const int* in_sizes, int n_in,
                              void* d_out, int out_size, void* d_ws, size_t ws_size,
                              hipStream_t stream) {
    (void)in_sizes; (void)n_in; (void)out_size; (void)ws_size;
    const float* x  = (const float*)d_in[0];
    const float* W0 = (const float*)d_in[1];
    const float* W1 = (const float*)d_in[2];
    const float* W2 = (const float*)d_in[3];
    const float* b0 = (const float*)d_in[4];
    const float* b1 = (const float*)d_in[5];
    const float* b2 = (const float*)d_in[6];
    float* out = (float*)d_out;

    char* wsb = (char*)d_ws;
    float*          coef  = (float*)(wsb + 0);
    unsigned short* xf    = (unsigned short*)(wsb + 16384);
    unsigned short* H1f   = (unsigned short*)(wsb + 802816);
    unsigned short* H2f   = (unsigned short*)(wsb + 1982464);
    unsigned short* Wf0   = (unsigned short*)(wsb + 3162112);
    unsigned short* Wf1   = (unsigned short*)(wsb + 4734976);
    unsigned short* Wf2   = (unsigned short*)(wsb + 7094272);
    unsigned*       flags = (unsigned*)(wsb + 8568832);

    int maxb = 0;
    hipError_t qe = hipOccupancyMaxActiveBlocksPerMultiprocessor(
        &maxb, (const void*)pfnn_fused, 256, 0);

    if (qe == hipSuccess && maxb >= 2) {
        zero_flags<<<dim3(1), dim3(256), 0, stream>>>(flags);
        void* args[] = {
            (void*)&x, (void*)&W0, (void*)&W1, (void*)&W2,
            (void*)&b0, (void*)&b1, (void*)&b2, (void*)&out,
            (void*)&coef, (void*)&xf, (void*)&H1f, (void*)&H2f,
            (void*)&Wf0, (void*)&Wf1, (void*)&Wf2, (void*)&flags
        };
        hipError_t e = hipLaunchCooperativeKernel((const void*)pfnn_fused,
                                                  dim3(512), dim3(256), args, 0, stream);
        if (e == hipSuccess) return;
        (void)hipGetLastError();
    }
    phaseA_kernel<<<dim3(200), dim3(256), 0, stream>>>(x, W0, W1, W2, b0, b1, b2, out, coef, xf, H1f, H2f, Wf0, Wf1, Wf2);
    layer0_kernel<<<dim3(512), dim3(256), 0, stream>>>(x, W0, W1, W2, b0, b1, b2, out, coef, xf, H1f, H2f, Wf0, Wf1, Wf2);
    layer1_kernel<<<dim3(512), dim3(256), 0, stream>>>(x, W0, W1, W2, b0, b1, b2, out, coef, xf, H1f, H2f, Wf0, Wf1, Wf2);
    layer2_kernel<<<dim3(320), dim3(256), 0, stream>>>(x, W0, W1, W2, b0, b1, b2, out, coef, xf, H1f, H2f, Wf0, Wf1, Wf2);
}

// Round 11
// 99.761 us; speedup vs baseline: 3.2386x; 1.0036x over previous
//
#include <hip/hip_runtime.h>
#include <math.h>

typedef short bf16x8 __attribute__((ext_vector_type(8)));
typedef float f32x16 __attribute__((ext_vector_type(16)));
typedef float f32x4  __attribute__((ext_vector_type(4)));

#define MAGIC 0x51C0FFEEu

__device__ __forceinline__ unsigned short f2bf(float f) {
    union { float f; unsigned u; } x; x.f = f;
    unsigned r = x.u + 0x7FFFu + ((x.u >> 16) & 1u);
    return (unsigned short)(r >> 16);
}

// ---- dataflow sync via per-producer MAGIC slots (no init needed: poison != MAGIC) ----
// Producer: release-store MAGIC (orders prior data stores). Consumer: relaxed polls,
// NO acquire-inv — dispatch-start cache invalidation + first-touch-after-flag makes
// consumer caches unable to hold stale frag lines.
__device__ __forceinline__ void slot_sig(unsigned* s) {
    __syncthreads();                     // drain block's data stores (vmcnt 0)
    if (threadIdx.x == 0)
        __hip_atomic_store(s, MAGIC, __ATOMIC_RELEASE, __HIP_MEMORY_SCOPE_AGENT);
}
__device__ __forceinline__ void slot_sig3(unsigned* a, unsigned* b, unsigned* c) {
    __syncthreads();
    if (threadIdx.x == 0) {
        __hip_atomic_store(a, MAGIC, __ATOMIC_RELEASE, __HIP_MEMORY_SCOPE_AGENT);
        __hip_atomic_store(b, MAGIC, __ATOMIC_RELEASE, __HIP_MEMORY_SCOPE_AGENT);
        __hip_atomic_store(c, MAGIC, __ATOMIC_RELEASE, __HIP_MEMORY_SCOPE_AGENT);
    }
}
__device__ __forceinline__ void wait_slots(unsigned* b1, int n1, unsigned* b2, int n2) {
    if (threadIdx.x == 0) {
        for (int i = 0; i < n1; ++i)
            while (__hip_atomic_load(b1 + i, __ATOMIC_RELAXED, __HIP_MEMORY_SCOPE_AGENT) != MAGIC)
                __builtin_amdgcn_s_sleep(1);
        for (int i = 0; i < n2; ++i)
            while (__hip_atomic_load(b2 + i, __ATOMIC_RELAXED, __HIP_MEMORY_SCOPE_AGENT) != MAGIC)
                __builtin_amdgcn_s_sleep(1);
    }
    __syncthreads();
}

// Slot map (u32 offsets in flags[]):
//   W0S=0   [16 ot][4 n]   W1S=64  [16][4]   W2S=128 [10][4]
//   XS=192  [32 bt]        H1S=256 [32 bt][17 p]   H2S=832 [32][17]  (p=ot, 16=tail)
#define W0S 0
#define W1S 64
#define W2S 128
#define XS  192
#define H1S 256
#define H2S 832

// ---- masked 8-float chunk load (bias fold at k==Kreal) ----
__device__ __forceinline__ void load8(const float* __restrict__ W, const float* __restrict__ bias,
                                      int rowbase, int rowlimit, int Kreal, int ldsrc,
                                      int r, int kb, float v[8])
{
    const bool rv = r < rowlimit;
    const float* src = W + (size_t)(rowbase + r) * ldsrc + kb;
    if (rv && kb + 7 < Kreal) {
        #pragma unroll
        for (int i = 0; i < 8; ++i) v[i] = src[i];
    } else {
        #pragma unroll
        for (int i = 0; i < 8; ++i) {
            int k = kb + i;
            v[i] = (rv && k < Kreal) ? src[i]
                 : ((rv && k == Kreal) ? (bias ? bias[rowbase + r] : 1.0f) : 0.f);
        }
    }
}

// ---- Transpose one 32-row fp32 tile into frag-major bf16 (r7-verified layout) ----
template<int NKS_T>
__device__ void transpose_tile(const float* __restrict__ W, const float* __restrict__ bias,
                               int rowbase, int rowlimit, int Kreal, int ldsrc,
                               unsigned short* __restrict__ dst, float* s, int tid)
{
    constexpr int NCHK = NKS_T / 4;
    const int r = tid >> 3, l = tid & 7;
    const int ks_l = tid >> 6, lane = tid & 63;
    const int m = lane & 31, h = lane >> 5;

    float cur[8], nxt[8];
    load8(W, bias, rowbase, rowlimit, Kreal, ldsrc, r, l * 8, cur);
    for (int kc = 0; kc < NCHK; ++kc) {
        if (kc + 1 < NCHK)
            load8(W, bias, rowbase, rowlimit, Kreal, ldsrc, r, (kc + 1) * 64 + l * 8, nxt);
        #pragma unroll
        for (int i = 0; i < 8; ++i) s[r * 66 + l * 8 + i] = cur[i];
        __syncthreads();
        {
            bf16x8 pk;
            #pragma unroll
            for (int j = 0; j < 8; ++j)
                pk[j] = (short)f2bf(s[m * 66 + ks_l * 16 + h * 8 + j]);
            __builtin_nontemporal_store(pk,
                (bf16x8*)(dst + ((size_t)(kc * 4 + ks_l) * 64 + lane) * 8));
        }
        __syncthreads();
        #pragma unroll
        for (int i = 0; i < 8; ++i) cur[i] = nxt[i];
    }
}

// ---- Phase A unit u in [0,200) (r7-verified bodies) ----
__device__ void phaseA_unit(
    int u, int tid, float* s,
    const float* __restrict__ x,
    const float* __restrict__ W0, const float* __restrict__ W1, const float* __restrict__ W2,
    const float* __restrict__ bias0, const float* __restrict__ bias1, const float* __restrict__ bias2,
    float* __restrict__ coef, unsigned short* __restrict__ xf,
    unsigned short* __restrict__ H1f, unsigned short* __restrict__ H2f,
    unsigned short* __restrict__ Wf0, unsigned short* __restrict__ Wf1, unsigned short* __restrict__ Wf2)
{
    if (u < 32) {
        const int bt = u;
        if (tid < 32) {
            int b = bt * 32 + tid;
            float phase = x[(size_t)b * 343 + 342];
            float ps = 4.0f * phase;
            int k1 = (int)ps;
            float mu = ps - (float)k1;
            k1 &= 3;
            float mu2 = mu * mu, mu3 = mu2 * mu;
            float c0 = -0.5f * mu3 +        mu2 - 0.5f * mu;
            float c1 =  1.5f * mu3 - 2.5f * mu2 + 1.0f;
            float c2 = -1.5f * mu3 + 2.0f * mu2 + 0.5f * mu;
            float c3 =  0.5f * mu3 - 0.5f * mu2;
            float cc[4];
            cc[(k1 + 3) & 3] = c0;
            cc[k1]           = c1;
            cc[(k1 + 1) & 3] = c2;
            cc[(k1 + 2) & 3] = c3;
            f32x4 cv; cv[0] = cc[0]; cv[1] = cc[1]; cv[2] = cc[2]; cv[3] = cc[3];
            __builtin_nontemporal_store(cv, (f32x4*)(coef + b * 4));
        }
        {
            int kk = tid >> 6, lane = tid & 63;
            size_t off = ((size_t)(bt * 36 + 32 + kk) * 64 + lane) * 8;
            bf16x8 v;
            #pragma unroll
            for (int j = 0; j < 8; ++j)
                v[j] = (short)((kk == 0 && (lane >> 5) == 0 && j == 0) ? 0x3F80 : 0);
            __builtin_nontemporal_store(v, (bf16x8*)(H1f + off));
            __builtin_nontemporal_store(v, (bf16x8*)(H2f + off));
        }
        transpose_tile<24>(x, nullptr, bt * 32, 32, 342, 343,
                           xf + (size_t)bt * 24 * 512, s, tid);
    } else if (u < 96) {
        int idx = u - 32, n = idx >> 4, ot = idx & 15;
        transpose_tile<24>(W0, bias0, n * 512 + ot * 32, 32, 342, 342,
                           Wf0 + (size_t)(n * 16 + ot) * 24 * 512, s, tid);
    } else if (u < 160) {
        int idx = u - 96, n = idx >> 4, ot = idx & 15;
        transpose_tile<36>(W1, bias1, n * 512 + ot * 32, 32, 512, 512,
                           Wf1 + (size_t)(n * 16 + ot) * 36 * 512, s, tid);
    } else {
        int idx = u - 160, n = idx / 10, ot = idx % 10;
        int rl = 311 - ot * 32; if (rl > 32) rl = 32;
        transpose_tile<36>(W2, bias2, n * 311 + ot * 32, rl, 512, 512,
                           Wf2 + (size_t)(n * 10 + ot) * 36 * 512, s, tid);
    }
}

// ---- One layer tile (r7-verified): 32o x 32b x 4 banks, 4-wave split-K ----
template<bool ELU, bool OUT_BF16, int KP, int OPAD>
__device__ __forceinline__ void layer_tile(
    const unsigned short* __restrict__ Wf,
    const unsigned short* __restrict__ Hf,
    const float* __restrict__ coef,
    unsigned short* __restrict__ HoutF,
    float* __restrict__ outF, int Oreal,
    float* red, int t, int tid)
{
    constexpr int NOT = OPAD / 32, NKS = KP / 16, KSQ = NKS / 4;
    constexpr int CH = 3, NC2 = KSQ / CH;
    const int lane = tid & 63, w = tid >> 6;
    const int m = lane & 31, h = lane >> 5;
    const size_t nstr = (size_t)NOT * NKS * 512;

    const int ot = t >> 5, bt = t & 31;
    const unsigned short* wbase = Wf + ((size_t)ot * NKS + w * KSQ) * 512 + (size_t)lane * 8;
    const unsigned short* bbase = Hf + ((size_t)bt * NKS + w * KSQ) * 512 + (size_t)lane * 8;

    f32x16 acc0 = {}, acc1 = {}, acc2 = {}, acc3 = {};
    bf16x8 Ab[2][CH][4], Bb[2][CH];

    #pragma unroll
    for (int sI = 0; sI < CH; ++sI) {
        Bb[0][sI] = *(const bf16x8*)(bbase + (size_t)sI * 512);
        #pragma unroll
        for (int n = 0; n < 4; ++n)
            Ab[0][sI][n] = *(const bf16x8*)(wbase + (size_t)n * nstr + (size_t)sI * 512);
    }
    #pragma unroll
    for (int c = 0; c < NC2; ++c) {
        const int cur = c & 1;
        if (c + 1 < NC2) {
            const int nxt = cur ^ 1;
            #pragma unroll
            for (int sI = 0; sI < CH; ++sI) {
                int st = (c + 1) * CH + sI;
                Bb[nxt][sI] = *(const bf16x8*)(bbase + (size_t)st * 512);
                #pragma unroll
                for (int n = 0; n < 4; ++n)
                    Ab[nxt][sI][n] = *(const bf16x8*)(wbase + (size_t)n * nstr + (size_t)st * 512);
            }
        }
        #pragma unroll
        for (int sI = 0; sI < CH; ++sI) {
            acc0 = __builtin_amdgcn_mfma_f32_32x32x16_bf16(Ab[cur][sI][0], Bb[cur][sI], acc0, 0, 0, 0);
            acc1 = __builtin_amdgcn_mfma_f32_32x32x16_bf16(Ab[cur][sI][1], Bb[cur][sI], acc1, 0, 0, 0);
            acc2 = __builtin_amdgcn_mfma_f32_32x32x16_bf16(Ab[cur][sI][2], Bb[cur][sI], acc2, 0, 0, 0);
            acc3 = __builtin_amdgcn_mfma_f32_32x32x16_bf16(Ab[cur][sI][3], Bb[cur][sI], acc3, 0, 0, 0);
        }
    }

    const int b = bt * 32 + m;
    float4 cf = *(const float4*)(coef + b * 4);
    #pragma unroll
    for (int g = 0; g < 4; ++g)
        #pragma unroll
        for (int j = 0; j < 4; ++j) {
            int rI = g * 4 + j;
            float v = cf.x * acc0[rI] + cf.y * acc1[rI] + cf.z * acc2[rI] + cf.w * acc3[rI];
            red[w * 1024 + (8 * g + 4 * h + j) * 32 + m] = v;
        }
    __syncthreads();
    {
        float vv[4];
        #pragma unroll
        for (int j = 0; j < 4; ++j) {
            int row = 8 * w + 4 * h + j;
            float v = red[row * 32 + m] + red[1024 + row * 32 + m]
                    + red[2048 + row * 32 + m] + red[3072 + row * 32 + m];
            if (ELU) v = (v > 0.f) ? v : expm1f(v);
            vv[j] = v;
        }
        if (OUT_BF16) {
            size_t off = (((size_t)bt * 36 + ot * 2 + (w >> 1)) * 64
                          + (w & 1) * 32 + m) * 8 + 4 * h;
            ushort4 pk;
            pk.x = f2bf(vv[0]); pk.y = f2bf(vv[1]); pk.z = f2bf(vv[2]); pk.w = f2bf(vv[3]);
            __builtin_nontemporal_store(*(unsigned long long*)&pk,
                                        (unsigned long long*)(HoutF + off));
        } else {
            int orow = ot * 32 + 8 * w + 4 * h;
            #pragma unroll
            for (int j = 0; j < 4; ++j)
                if (orow + j < Oreal) outF[(size_t)b * Oreal + orow + j] = vv[j];
        }
    }
}

#define PFNN_PARAMS \
    const float* __restrict__ x, \
    const float* __restrict__ W0, const float* __restrict__ W1, const float* __restrict__ W2, \
    const float* __restrict__ bias0, const float* __restrict__ bias1, const float* __restrict__ bias2, \
    float* __restrict__ outF, float* __restrict__ coef, \
    unsigned short* __restrict__ xf, \
    unsigned short* __restrict__ H1f, unsigned short* __restrict__ H2f, \
    unsigned short* __restrict__ Wf0, unsigned short* __restrict__ Wf1, unsigned short* __restrict__ Wf2

// Dataflow-fused persistent kernel; MAGIC-slot sync (no flag init, single dispatch).
__global__ void __launch_bounds__(256, 2) pfnn_fused(PFNN_PARAMS, unsigned* flags) {
    __shared__ union { float s[32 * 66]; float red[4 * 1024]; } u;   // 16 KB
    const int b = blockIdx.x, tid = threadIdx.x;

    if (b < 200) {
        phaseA_unit(b, tid, u.s, x, W0, W1, W2, bias0, bias1, bias2,
                    coef, xf, H1f, H2f, Wf0, Wf1, Wf2);
        if (b < 32)
            slot_sig3(flags + XS + b, flags + H1S + b * 17 + 16, flags + H2S + b * 17 + 16);
        else if (b < 96)
            slot_sig(flags + W0S + ((b - 32) & 15) * 4 + ((b - 32) >> 4));
        else if (b < 160)
            slot_sig(flags + W1S + ((b - 96) & 15) * 4 + ((b - 96) >> 4));
        else
            slot_sig(flags + W2S + ((b - 160) % 10) * 4 + ((b - 160) / 10));
    }

    {   // layer 0, tile b
        const int ot = b >> 5, bt = b & 31;
        wait_slots(flags + W0S + ot * 4, 4, flags + XS + bt, 1);
        layer_tile<true, true, 384, 512>(Wf0, xf, coef, H1f, nullptr, 512, u.red, b, tid);
        slot_sig(flags + H1S + bt * 17 + ot);
    }
    {   // layer 1, tile b
        const int ot = b >> 5, bt = b & 31;
        wait_slots(flags + W1S + ot * 4, 4, flags + H1S + bt * 17, 17);
        layer_tile<true, true, 576, 512>(Wf1, H1f, coef, H2f, nullptr, 512, u.red, b, tid);
        slot_sig(flags + H2S + bt * 17 + ot);
    }
    if (b < 320) {   // layer 2, tile b
        const int ot = b >> 5, bt = b & 31;
        wait_slots(flags + W2S + ot * 4, 4, flags + H2S + bt * 17, 17);
        layer_tile<false, false, 576, 320>(Wf2, H2f, coef, nullptr, outF, 311, u.red, b, tid);
    }
}

// -------- fallback: 4-dispatch path (r7-proven, no flags needed) --------
__global__ void __launch_bounds__(256) phaseA_kernel(PFNN_PARAMS) {
    __shared__ float s[32 * 66];
    for (int un = blockIdx.x; un < 200; un += gridDim.x)
        phaseA_unit(un, threadIdx.x, s, x, W0, W1, W2, bias0, bias1, bias2,
                    coef, xf, H1f, H2f, Wf0, Wf1, Wf2);
    (void)outF;
}
__global__ void __launch_bounds__(256, 2) layer0_kernel(PFNN_PARAMS) {
    __shared__ float red[4 * 1024];
    layer_tile<true, true, 384, 512>(Wf0, xf, coef, H1f, nullptr, 512, red, blockIdx.x, threadIdx.x);
    (void)outF;
}
__global__ void __launch_bounds__(256, 2) layer1_kernel(PFNN_PARAMS) {
    __shared__ float red[4 * 1024];
    layer_tile<true, true, 576, 512>(Wf1, H1f, coef, H2f, nullptr, 512, red, blockIdx.x, threadIdx.x);
    (void)outF;
}
__global__ void __launch_bounds__(256, 2) layer2_kernel(PFNN_PARAMS) {
    __shared__ float red[4 * 1024];
    layer_tile<false, false, 576, 320>(Wf2, H2f, coef, nullptr, outF, 311, red, blockIdx.x, threadIdx.x);
}

extern "C" void kernel_launch(void* const* d_in, const int* in_sizes, int n_in,
                              void* d_out, int out_size, void* d_ws, size_t ws_size,
                              hipStream_t stream) {
    (void)in_sizes; (void)n_in; (void)out_size; (void)ws_size;
    const float* x  = (const float*)d_in[0];
    const float* W0 = (const float*)d_in[1];
    const float* W1 = (const float*)d_in[2];
    const float* W2 = (const float*)d_in[3];
    const float* b0 = (const float*)d_in[4];
    const float* b1 = (const float*)d_in[5];
    const float* b2 = (const float*)d_in[6];
    float* out = (float*)d_out;

    char* wsb = (char*)d_ws;
    float*          coef  = (float*)(wsb + 0);
    unsigned short* xf    = (unsigned short*)(wsb + 16384);
    unsigned short* H1f   = (unsigned short*)(wsb + 802816);
    unsigned short* H2f   = (unsigned short*)(wsb + 1982464);
    unsigned short* Wf0   = (unsigned short*)(wsb + 3162112);
    unsigned short* Wf1   = (unsigned short*)(wsb + 4734976);
    unsigned short* Wf2   = (unsigned short*)(wsb + 7094272);
    unsigned*       flags = (unsigned*)(wsb + 8568832);

    int maxb = 0;
    hipError_t qe = hipOccupancyMaxActiveBlocksPerMultiprocessor(
        &maxb, (const void*)pfnn_fused, 256, 0);

    if (qe == hipSuccess && maxb >= 2) {
        void* args[] = {
            (void*)&x, (void*)&W0, (void*)&W1, (void*)&W2,
            (void*)&b0, (void*)&b1, (void*)&b2, (void*)&out,
            (void*)&coef, (void*)&xf, (void*)&H1f, (void*)&H2f,
            (void*)&Wf0, (void*)&Wf1, (void*)&Wf2, (void*)&flags
        };
        hipError_t e = hipLaunchCooperativeKernel((const void*)pfnn_fused,
                                                  dim3(512), dim3(256), args, 0, stream);
        if (e == hipSuccess) return;
        (void)hipGetLastError();
    }
    phaseA_kernel<<<dim3(200), dim3(256), 0, stream>>>(x, W0, W1, W2, b0, b1, b2, out, coef, xf, H1f, H2f, Wf0, Wf1, Wf2);
    layer0_kernel<<<dim3(512), dim3(256), 0, stream>>>(x, W0, W1, W2, b0, b1, b2, out, coef, xf, H1f, H2f, Wf0, Wf1, Wf2);
    layer1_kernel<<<dim3(512), dim3(256), 0, stream>>>(x, W0, W1, W2, b0, b1, b2, out, coef, xf, H1f, H2f, Wf0, Wf1, Wf2);
    layer2_kernel<<<dim3(320), dim3(256), 0, stream>>>(x, W0, W1, W2, b0, b1, b2, out, coef, xf, H1f, H2f, Wf0, Wf1, Wf2);
}